// Round 6
// baseline (57.168 us; speedup 1.0000x reference)
//
#include <hip/hip_runtime.h>

// input_feats: [B=2, F=32, D=32, H=128, W=128] f32
// sampling_grid: [B=2, 256, 256, 3] f32
// out: [B=2, F=32, 256, 256] f32
#define B_  2
#define F_  32
#define D_  32
#define H_  128
#define W_  128
#define NPIX 65536
#define TOTALPIX (B_ * NPIX)
#define SLAB (D_ * H_ * W_)                       // 524288 sites per (b,f)
#define T_BYTES ((size_t)B_ * SLAB * F_ * 2)      // 67 MB bf16 transposed copy

typedef float  f32x4  __attribute__((ext_vector_type(4)));
typedef ushort u16x8  __attribute__((ext_vector_type(8)));

// f32 -> bf16 round-nearest-even (inputs are finite random normals)
__device__ __forceinline__ ushort f2bf(float f) {
    unsigned u = __float_as_uint(f);
    u += 0x7fffu + ((u >> 16) & 1u);
    return (ushort)(u >> 16);
}
__device__ __forceinline__ float bf2f(ushort h) {
    return __uint_as_float((unsigned)h << 16);
}

// ---------- common grid math (matches reference fp32 op order) ----------
__device__ __forceinline__ void corner_setup(const float* __restrict__ g,
                                             int* off, float* wt)
{
    float gx = fminf(fmaxf(g[0], -1.f), 1.f);
    float gy = fminf(fmaxf(g[1], -1.f), 1.f);
    float gz = fminf(fmaxf(g[2], -1.f), 1.f);
    float x = ((gx + 1.f) * 0.5f) * 127.f;
    float y = ((gy + 1.f) * 0.5f) * 127.f;
    float z = ((gz + 1.f) * 0.5f) * 31.f;

    float x0f = floorf(x), y0f = floorf(y), z0f = floorf(z);
    float u = x - x0f, v = y - y0f, w = z - z0f;
    int x0 = (int)x0f, y0 = (int)y0f, z0 = (int)z0f;

    float wx[2] = {1.f - u, u};
    float wy[2] = {1.f - v, v};
    float wz[2] = {1.f - w, w};
    // xi/yi == 127 is INVALID (grid_sample round-half-even -> 128, OOB) -> weight 0.
    // zi is clamped (stays valid).
    int   xs[2] = {x0 < 127 ? x0 : 127, x0 + 1 < 127 ? x0 + 1 : 127};
    int   ys[2] = {y0 < 127 ? y0 : 127, y0 + 1 < 127 ? y0 + 1 : 127};
    int   zs[2] = {z0 < 31 ? z0 : 31, z0 + 1 < 31 ? z0 + 1 : 31};
    bool  vx[2] = {x0 <= 126, x0 + 1 <= 126};
    bool  vy[2] = {y0 <= 126, y0 + 1 <= 126};

    #pragma unroll
    for (int dx = 0; dx < 2; ++dx)
        #pragma unroll
        for (int dy = 0; dy < 2; ++dy)
            #pragma unroll
            for (int dz = 0; dz < 2; ++dz) {
                int c = dx * 4 + dy * 2 + dz;
                off[c] = zs[dz] * (H_ * W_) + ys[dy] * W_ + xs[dx];
                float wgt = wx[dx] * wy[dy] * wz[dz];
                wt[c] = (vx[dx] && vy[dy]) ? wgt : 0.f;
            }
}

// ---------- kernel 1: transpose+quantize [B,F,S] f32 -> [B,S,F] bf16 ----------
// No nontemporal hints (round-4 post-timing fail: nt stores incoherent with
// the harness poison fill). Stores are u16x8 = 1KB contiguous per wave-instr.
__global__ __launch_bounds__(256) void transpose_bf16_kernel(
    const float* __restrict__ in, ushort* __restrict__ T)
{
    __shared__ float lds[F_][132];                 // rows 16B-aligned
    int bid = blockIdx.x;
    int b   = bid >> 12;                           // / 4096
    int s0  = (bid & 4095) << 7;                   // * 128
    int tid = threadIdx.x;
    int sq  = tid & 31;                            // float4 slot along s
    int fh  = tid >> 5;                            // 0..7

    const float* src = in + (size_t)b * ((size_t)F_ * SLAB) + s0 + sq * 4;
    #pragma unroll
    for (int r = 0; r < 4; ++r) {
        int f = r * 8 + fh;
        f32x4 v = *reinterpret_cast<const f32x4*>(src + (size_t)f * SLAB);
        *reinterpret_cast<f32x4*>(&lds[f][sq * 4]) = v;
    }
    __syncthreads();

    ushort* dst = T + ((size_t)b * SLAB + s0) * F_;
    #pragma unroll
    for (int i = 0; i < 2; ++i) {
        int idx = i * 256 + tid;                   // 512 chunks: 128 sp x 4 f8
        int f8  = idx & 3;                         // feature group of 8
        int sp  = idx >> 2;                        // site 0..127
        u16x8 h;
        #pragma unroll
        for (int k = 0; k < 8; ++k)
            h[k] = f2bf(lds[f8 * 8 + k][sp]);
        *reinterpret_cast<u16x8*>(dst + (size_t)sp * F_ + f8 * 8) = h;
    }
}

// ---------- kernel 2: gather from [B,S,F] bf16 ----------
// 4 threads/pixel, 16B/lane corner loads. Each thread handles the SAME pixel
// index in BOTH batches -> 16 independent scattered loads in flight (2x MLP).
__global__ __launch_bounds__(256) void gather_bf16_kernel(
    const ushort* __restrict__ T, const float* __restrict__ grid,
    float* __restrict__ out)
{
    int tid = threadIdx.x;
    int fg  = tid & 3;                             // feature group (8 bf16 = 16B)
    int pl  = tid >> 2;                            // pixel within block (0..63)
    int pix = blockIdx.x * 64 + pl;                // 0..65535

    int   off0[8], off1[8];
    float wt0[8],  wt1[8];
    corner_setup(grid + (size_t)pix * 3,          off0, wt0);   // batch 0
    corner_setup(grid + (size_t)(NPIX + pix) * 3, off1, wt1);   // batch 1

    const ushort* base0 = T + fg * 8;
    const ushort* base1 = T + (size_t)SLAB * F_ + fg * 8;

    float acc0[8], acc1[8];
    #pragma unroll
    for (int k = 0; k < 8; ++k) { acc0[k] = 0.f; acc1[k] = 0.f; }

    #pragma unroll
    for (int c = 0; c < 8; ++c) {
        u16x8 hv0 = *reinterpret_cast<const u16x8*>(base0 + (size_t)off0[c] * F_);
        u16x8 hv1 = *reinterpret_cast<const u16x8*>(base1 + (size_t)off1[c] * F_);
        #pragma unroll
        for (int k = 0; k < 8; ++k) {
            acc0[k] += wt0[c] * bf2f(hv0[k]);
            acc1[k] += wt1[c] * bf2f(hv1[k]);
        }
    }

    float* ob0 = out + pix;
    float* ob1 = out + (size_t)F_ * NPIX + pix;
    #pragma unroll
    for (int k = 0; k < 8; ++k) {
        ob0[(size_t)(fg * 8 + k) * NPIX] = acc0[k];
        ob1[(size_t)(fg * 8 + k) * NPIX] = acc1[k];
    }
}

// ---------- fallback (round-1 kernel) if workspace too small ----------
__global__ __launch_bounds__(256) void trilerp_direct_kernel(
    const float* __restrict__ feats, const float* __restrict__ grid,
    float* __restrict__ out)
{
    int p   = blockIdx.x * blockDim.x + threadIdx.x;
    int b   = p >> 16;
    int pix = p & (NPIX - 1);

    int   off[8];
    float wt[8];
    corner_setup(grid + (size_t)p * 3, off, wt);

    const float* fb = feats + (size_t)b * ((size_t)F_ * SLAB);
    float* ob = out + (size_t)b * ((size_t)F_ * NPIX) + pix;

    #pragma unroll 4
    for (int f = 0; f < F_; ++f) {
        const float* s = fb + (size_t)f * SLAB;
        float acc = 0.f;
        #pragma unroll
        for (int c = 0; c < 8; ++c)
            acc += wt[c] * s[off[c]];
        ob[(size_t)f * NPIX] = acc;
    }
}

extern "C" void kernel_launch(void* const* d_in, const int* in_sizes, int n_in,
                              void* d_out, int out_size, void* d_ws, size_t ws_size,
                              hipStream_t stream) {
    const float* feats = (const float*)d_in[0];
    const float* grid  = (const float*)d_in[1];
    float* out = (float*)d_out;

    if (ws_size >= T_BYTES) {
        ushort* T = (ushort*)d_ws;
        transpose_bf16_kernel<<<dim3(B_ * (SLAB / 128)), dim3(256), 0, stream>>>(feats, T);
        gather_bf16_kernel<<<dim3(NPIX / 64), dim3(256), 0, stream>>>(T, grid, out);
    } else {
        trilerp_direct_kernel<<<dim3(TOTALPIX / 256), dim3(256), 0, stream>>>(feats, grid, out);
    }
}

// Round 7
// 51.679 us; speedup vs baseline: 1.1062x; 1.1062x over previous
//
#include <hip/hip_runtime.h>

// input_feats: [B=2, F=32, D=32, H=128, W=128] f32
// sampling_grid: [B=2, 256, 256, 3] f32
// out: [B=2, F=32, 256, 256] f32
#define B_  2
#define F_  32
#define D_  32
#define H_  128
#define W_  128
#define NPIX 65536
#define TOTALPIX (B_ * NPIX)
#define SLAB (D_ * H_ * W_)                       // 524288 sites per (b,f)
#define T_BYTES ((size_t)B_ * SLAB * F_ * 2)      // 67 MB bf16 transposed copy
#define LPITCH 130                                // LDS row pitch: 130 mod 32 = 2 -> 2-way (free) read conflicts

typedef float  f32x4  __attribute__((ext_vector_type(4)));
typedef ushort u16x8  __attribute__((ext_vector_type(8)));

// f32 -> bf16 round-nearest-even (inputs are finite random normals)
__device__ __forceinline__ ushort f2bf(float f) {
    unsigned u = __float_as_uint(f);
    u += 0x7fffu + ((u >> 16) & 1u);
    return (ushort)(u >> 16);
}
__device__ __forceinline__ float bf2f(ushort h) {
    return __uint_as_float((unsigned)h << 16);
}

// ---------- common grid math (matches reference fp32 op order) ----------
__device__ __forceinline__ void corner_setup(const float* __restrict__ g,
                                             int* off, float* wt)
{
    float gx = fminf(fmaxf(g[0], -1.f), 1.f);
    float gy = fminf(fmaxf(g[1], -1.f), 1.f);
    float gz = fminf(fmaxf(g[2], -1.f), 1.f);
    float x = ((gx + 1.f) * 0.5f) * 127.f;
    float y = ((gy + 1.f) * 0.5f) * 127.f;
    float z = ((gz + 1.f) * 0.5f) * 31.f;

    float x0f = floorf(x), y0f = floorf(y), z0f = floorf(z);
    float u = x - x0f, v = y - y0f, w = z - z0f;
    int x0 = (int)x0f, y0 = (int)y0f, z0 = (int)z0f;

    float wx[2] = {1.f - u, u};
    float wy[2] = {1.f - v, v};
    float wz[2] = {1.f - w, w};
    // xi/yi == 127 is INVALID (grid_sample round-half-even -> 128, OOB) -> weight 0.
    // zi is clamped (stays valid).
    int   xs[2] = {x0 < 127 ? x0 : 127, x0 + 1 < 127 ? x0 + 1 : 127};
    int   ys[2] = {y0 < 127 ? y0 : 127, y0 + 1 < 127 ? y0 + 1 : 127};
    int   zs[2] = {z0 < 31 ? z0 : 31, z0 + 1 < 31 ? z0 + 1 : 31};
    bool  vx[2] = {x0 <= 126, x0 + 1 <= 126};
    bool  vy[2] = {y0 <= 126, y0 + 1 <= 126};

    #pragma unroll
    for (int dx = 0; dx < 2; ++dx)
        #pragma unroll
        for (int dy = 0; dy < 2; ++dy)
            #pragma unroll
            for (int dz = 0; dz < 2; ++dz) {
                int c = dx * 4 + dy * 2 + dz;
                off[c] = zs[dz] * (H_ * W_) + ys[dy] * W_ + xs[dx];
                float wgt = wx[dx] * wy[dy] * wz[dz];
                wt[c] = (vx[dx] && vy[dy]) ? wgt : 0.f;
            }
}

// ---------- kernel 1: transpose+quantize [B,F,S] f32 -> [B,S,F] bf16 ----------
// No nontemporal hints (round-4 post-timing fail: nt stores incoherent with
// the harness poison fill). Stores are u16x8 = 1KB contiguous per wave-instr.
// LDS rows padded to 130 floats: read bank = f8*16 + 2k + sp -> 2 lanes/bank (free).
__global__ __launch_bounds__(256) void transpose_bf16_kernel(
    const float* __restrict__ in, ushort* __restrict__ T)
{
    __shared__ float lds[F_][LPITCH];
    int bid = blockIdx.x;
    int b   = bid >> 12;                           // / 4096
    int s0  = (bid & 4095) << 7;                   // * 128
    int tid = threadIdx.x;
    int sq  = tid & 31;                            // float4 slot along s
    int fh  = tid >> 5;                            // 0..7

    const float* src = in + (size_t)b * ((size_t)F_ * SLAB) + s0 + sq * 4;
    #pragma unroll
    for (int r = 0; r < 4; ++r) {
        int f = r * 8 + fh;
        f32x4 v = *reinterpret_cast<const f32x4*>(src + (size_t)f * SLAB);
        *reinterpret_cast<f32x4*>(&lds[f][sq * 4]) = v;
    }
    __syncthreads();

    ushort* dst = T + ((size_t)b * SLAB + s0) * F_;
    #pragma unroll
    for (int i = 0; i < 2; ++i) {
        int idx = i * 256 + tid;                   // 512 chunks: 128 sp x 4 f8
        int f8  = idx & 3;                         // feature group of 8
        int sp  = idx >> 2;                        // site 0..127
        u16x8 h;
        #pragma unroll
        for (int k = 0; k < 8; ++k)
            h[k] = f2bf(lds[f8 * 8 + k][sp]);
        *reinterpret_cast<u16x8*>(dst + (size_t)sp * F_ + f8 * 8) = h;
    }
}

// ---------- kernel 2: gather from [B,S,F] bf16 (round-5 version, best measured) ----------
// 4 threads/pixel, each corner load = ushort8 (16B/lane); corner chunk = one
// 64B line consumed by 4 lanes. Out stores: 4 full 64B lines per wave-instr.
// 1 pixel/thread: keeps VGPR < 64 (occupancy cliff) and 2048 blocks of TLP.
__global__ __launch_bounds__(256) void gather_bf16_kernel(
    const ushort* __restrict__ T, const float* __restrict__ grid,
    float* __restrict__ out)
{
    int tid = threadIdx.x;
    int fg  = tid & 3;                             // feature group (8 bf16 = 16B)
    int pl  = tid >> 2;                            // pixel within block (0..63)
    int p   = blockIdx.x * 64 + pl;
    int b   = p >> 16;
    int pix = p & (NPIX - 1);

    int   off[8];
    float wt[8];
    corner_setup(grid + (size_t)p * 3, off, wt);

    const ushort* base = T + (size_t)b * ((size_t)SLAB * F_) + fg * 8;
    float acc[8];
    #pragma unroll
    for (int k = 0; k < 8; ++k) acc[k] = 0.f;

    #pragma unroll
    for (int c = 0; c < 8; ++c) {
        u16x8 hv = *reinterpret_cast<const u16x8*>(base + (size_t)off[c] * F_);
        #pragma unroll
        for (int k = 0; k < 8; ++k)
            acc[k] += wt[c] * bf2f(hv[k]);
    }

    float* ob = out + (size_t)b * ((size_t)F_ * NPIX) + pix;
    #pragma unroll
    for (int k = 0; k < 8; ++k)
        ob[(size_t)(fg * 8 + k) * NPIX] = acc[k];
}

// ---------- fallback (round-1 kernel) if workspace too small ----------
__global__ __launch_bounds__(256) void trilerp_direct_kernel(
    const float* __restrict__ feats, const float* __restrict__ grid,
    float* __restrict__ out)
{
    int p   = blockIdx.x * blockDim.x + threadIdx.x;
    int b   = p >> 16;
    int pix = p & (NPIX - 1);

    int   off[8];
    float wt[8];
    corner_setup(grid + (size_t)p * 3, off, wt);

    const float* fb = feats + (size_t)b * ((size_t)F_ * SLAB);
    float* ob = out + (size_t)b * ((size_t)F_ * NPIX) + pix;

    #pragma unroll 4
    for (int f = 0; f < F_; ++f) {
        const float* s = fb + (size_t)f * SLAB;
        float acc = 0.f;
        #pragma unroll
        for (int c = 0; c < 8; ++c)
            acc += wt[c] * s[off[c]];
        ob[(size_t)f * NPIX] = acc;
    }
}

extern "C" void kernel_launch(void* const* d_in, const int* in_sizes, int n_in,
                              void* d_out, int out_size, void* d_ws, size_t ws_size,
                              hipStream_t stream) {
    const float* feats = (const float*)d_in[0];
    const float* grid  = (const float*)d_in[1];
    float* out = (float*)d_out;

    if (ws_size >= T_BYTES) {
        ushort* T = (ushort*)d_ws;
        transpose_bf16_kernel<<<dim3(B_ * (SLAB / 128)), dim3(256), 0, stream>>>(feats, T);
        gather_bf16_kernel<<<dim3(TOTALPIX / 64), dim3(256), 0, stream>>>(T, grid, out);
    } else {
        trilerp_direct_kernel<<<dim3(TOTALPIX / 256), dim3(256), 0, stream>>>(feats, grid, out);
    }
}